// Round 12
// baseline (1591.322 us; speedup 1.0000x reference)
//
#include <hip/hip_runtime.h>
#include <hip/hip_bf16.h>
#include <stdint.h>

// LSTM forward, B=64 T=512 D=512 H=512, return_sequences.
// v12 = v11 + two latency cuts on the sync chain (protocol unchanged):
//  (1) end-of-step drain vmcnt(0) -> vmcnt(2): only x loads are waited;
//      publish/out store acks retire inside next step's poll window.
//      Safe: every h word is self-stamped (flag-in-data), consumers
//      re-verify, skew bounded at 1 step by transitive block coupling.
//  (2) per-producer poll check: if producer A (p0/p1) valid, run HU(A)
//      while re-issuing only B's loads. Fixed A-then-B accumulation order
//      (determinism). Retry rounds move 2 loads instead of 4.
// Partition as v11: 64 blocks = 4 groups (g=blk&3, XCDs {g,g+4}) x 16
// slices (32 cols); 512 thr = 8 waves, k-chunk 64; weights in VGPRs;
// stamped u32 MALL comm (sc0 sc1); EX exchange; lockstep barriers.

#define Bdim 64
#define Tdim 512
#define Ddim 512
#define Hdim 512
#define G4H  2048
#define NG 4
#define NS 16
#define BH (Bdim * Hdim)  // u32 elems per parity plane

typedef __bf16 bf16_t;
typedef __bf16 bf16x8 __attribute__((ext_vector_type(8)));
typedef float  f32x4  __attribute__((ext_vector_type(4)));
typedef uint32_t u32x4 __attribute__((ext_vector_type(4)));
union pv128 { u32x4 u; f32x4 f; bf16x8 h; };
union bu16 { bf16_t b; unsigned short u; };

__device__ __forceinline__ float sigmoid_f(float x) {
  return 1.0f / (1.0f + __expf(-x));
}
__device__ __forceinline__ float tanh_f(float x) {
  return 1.0f - 2.0f / (__expf(2.0f * x) + 1.0f);  // stable both tails
}

// src [512][2048] fp32  ->  dst [2048][512] bf16 (transposed)
__global__ void transpose_bf16_512x2048(const float* __restrict__ src,
                                        bf16_t* __restrict__ dst) {
  __shared__ bf16_t tile[64][72];
  int c0 = blockIdx.x * 64;
  int r0 = blockIdx.y * 64;
  int tx = threadIdx.x & 63;
  int ty = threadIdx.x >> 6;
#pragma unroll
  for (int i = 0; i < 64; i += 4)
    tile[ty + i][tx] = (bf16_t)src[(size_t)(r0 + ty + i) * G4H + c0 + tx];
  __syncthreads();
#pragma unroll
  for (int i = 0; i < 64; i += 4)
    dst[(size_t)(c0 + ty + i) * Ddim + r0 + tx] = tile[tx][ty + i];
}

// fp32 -> bf16 elementwise (x pre-conversion), 8 elems/thread
__global__ void cast_bf16(const float* __restrict__ in, bf16_t* __restrict__ out) {
  size_t i = ((size_t)blockIdx.x * blockDim.x + threadIdx.x) * 8;
  f32x4 a = *(const f32x4*)(in + i);
  f32x4 b = *(const f32x4*)(in + i + 4);
  bf16x8 v;
#pragma unroll
  for (int j = 0; j < 4; ++j) { v[j] = (bf16_t)a[j]; v[j + 4] = (bf16_t)b[j]; }
  *(bf16x8*)(out + i) = v;
}

#define MFMA16(A, B, C) __builtin_amdgcn_mfma_f32_16x16x32_bf16(A, B, C, 0, 0, 0)

// producer A: 2 stamped loads (cols k0..k0+31)
#define ISSUE_POLL_A()                                                       \
  asm volatile(                                                              \
      "global_load_dwordx4 %0, %2, off sc0 sc1\n\t"                          \
      "global_load_dwordx4 %1, %2, off offset:16 sc0 sc1"                    \
      : "=v"(p0.f), "=v"(p1.f) : "v"(hb) : "memory")
// producer B: 2 stamped loads (cols k0+32..k0+63)
#define ISSUE_POLL_B()                                                       \
  asm volatile(                                                              \
      "global_load_dwordx4 %0, %2, off offset:128 sc0 sc1\n\t"               \
      "global_load_dwordx4 %1, %2, off offset:144 sc0 sc1"                   \
      : "=v"(p2.f), "=v"(p3.f) : "v"(hb) : "memory")

#define CHECKW(P, B)                                                         \
  do {                                                                       \
    B |= (P.u[0] ^ st) & 15u;                                                \
    B |= (P.u[1] ^ st) & 15u;                                                \
    B |= (P.u[2] ^ st) & 15u;                                                \
    B |= (P.u[3] ^ st) & 15u;                                                \
  } while (0)

// 8 MFMAs over the 8 N-tiles with A-operand AV and k-frag c
#define MM8(AV, WU, c)                                                       \
  a0 = MFMA16(AV, WU[0][c], a0);                                             \
  a1 = MFMA16(AV, WU[1][c], a1);                                             \
  a2 = MFMA16(AV, WU[2][c], a2);                                             \
  a3 = MFMA16(AV, WU[3][c], a3);                                             \
  a4 = MFMA16(AV, WU[4][c], a4);                                             \
  a5 = MFMA16(AV, WU[5][c], a5);                                             \
  a6 = MFMA16(AV, WU[6][c], a6);                                             \
  a7 = MFMA16(AV, WU[7][c], a7);

// unpack chunk c (8 u32 -> hi/lo bf16x8) and run 16 MFMAs
#define HU(PA, PB, c)                                                        \
  do {                                                                       \
    pv128 hi_, lo_;                                                          \
    hi_.u[0] = (PA.u[0] >> 16) | (PA.u[1] & 0xFFFF0000u);                    \
    hi_.u[1] = (PA.u[2] >> 16) | (PA.u[3] & 0xFFFF0000u);                    \
    hi_.u[2] = (PB.u[0] >> 16) | (PB.u[1] & 0xFFFF0000u);                    \
    hi_.u[3] = (PB.u[2] >> 16) | (PB.u[3] & 0xFFFF0000u);                    \
    lo_.u[0] = (PA.u[0] & 0xFFF0u) | ((PA.u[1] & 0xFFF0u) << 16);            \
    lo_.u[1] = (PA.u[2] & 0xFFF0u) | ((PA.u[3] & 0xFFF0u) << 16);            \
    lo_.u[2] = (PB.u[0] & 0xFFF0u) | ((PB.u[1] & 0xFFF0u) << 16);            \
    lo_.u[3] = (PB.u[2] & 0xFFF0u) | ((PB.u[3] & 0xFFF0u) << 16);            \
    MM8(hi_.h, Ur, c)                                                        \
    MM8(lo_.h, Ur, c)                                                        \
  } while (0)

__launch_bounds__(512, 1)
__global__ void lstm_fused(const bf16_t* __restrict__ xb,   // [B][T][D] bf16
                           const bf16_t* __restrict__ Wt,   // [2048][512] bf16
                           const bf16_t* __restrict__ Ut,   // [2048][512] bf16
                           const float* __restrict__ bias,  // [2048]
                           float* __restrict__ out,         // [B][T][H] fp32
                           uint32_t* __restrict__ hbuf) {   // [2 par][B][H] u32
  __shared__ float EX[8][4][16][36];  // [wave][gate][row][col pad36]

  const int blk  = blockIdx.x;
  const int g    = blk & 3;            // group spread: XCDs {g, g+4} only
  const int s    = blk >> 2;           // 0..15
  const int wv   = threadIdx.x >> 6;   // 0..7
  const int lane = threadIdx.x & 63;
  const int l15  = lane & 15;
  const int l4   = lane >> 4;
  const int b0   = g * 16;
  const int hc0  = s * 32;
  const int k0   = wv * 64;            // this wave's k-chunk

  // ---- weights into registers (MFMA B-frag order), 8 N-tiles x 2 k-frags ----
  bf16x8 Wr[8][2], Ur[8][2];
#pragma unroll
  for (int n = 0; n < 8; ++n) {
    int zc = (n >> 1) * Hdim + hc0 + (n & 1) * 16 + l15;
    const bf16_t* wsrc = Wt + (size_t)zc * Ddim + k0 + l4 * 8;
    const bf16_t* usrc = Ut + (size_t)zc * Ddim + k0 + l4 * 8;
#pragma unroll
    for (int c = 0; c < 2; ++c) {
      Wr[n][c] = *(const bf16x8*)(wsrc + c * 32);
      Ur[n][c] = *(const bf16x8*)(usrc + c * 32);
    }
  }

  // update-thread mapping: one h element per thread
  const int urow = threadIdx.x >> 5;   // 0..15
  const int ucol = threadIdx.x & 31;   // 0..31
  float b4[4];
#pragma unroll
  for (int G = 0; G < 4; ++G) b4[G] = bias[G * Hdim + hc0 + ucol];
  float cstate = 0.f;
  float* outp = out + (size_t)(b0 + urow) * Tdim * Hdim + hc0 + ucol;
  uint32_t* hpub = hbuf + (size_t)(b0 + urow) * Hdim + hc0 + ucol;
  const uint32_t* hrd = hbuf + (size_t)(b0 + l15) * Hdim + k0 + l4 * 8;
  const bf16_t* xrow = xb + (size_t)(b0 + l15) * Tdim * Ddim + k0 + l4 * 8;

  // ---- prologue: x(0) into regs (plain loads) ----
  pv128 xr0, xr1;
  asm volatile(
      "global_load_dwordx4 %0, %2, off\n\t"
      "global_load_dwordx4 %1, %2, off offset:64\n\t"
      "s_waitcnt vmcnt(0)"
      : "=v"(xr0.f), "=v"(xr1.f)
      : "v"(xrow) : "memory");
  __builtin_amdgcn_sched_barrier(0);

  bool dead = false;

  for (int t = 0; t < Tdim; ++t) {
    pv128 p0, p1, p2, p3;
    const uint32_t st = (uint32_t)t & 15u;  // stamp on h_{t-1}
    const uint32_t* hb = hrd + (((t - 1) & 1) ? BH : 0);

    // [P] issue stamped h polls; they fly during x@W
    if (t > 0 && !dead) {
      ISSUE_POLL_A();
      ISSUE_POLL_B();
      __builtin_amdgcn_sched_barrier(0);
    }

    // [A] x_t @ W (registers only)
    f32x4 a0 = {0, 0, 0, 0}, a1 = {0, 0, 0, 0}, a2 = {0, 0, 0, 0}, a3 = {0, 0, 0, 0};
    f32x4 a4 = {0, 0, 0, 0}, a5 = {0, 0, 0, 0}, a6 = {0, 0, 0, 0}, a7 = {0, 0, 0, 0};
    MM8(xr0.h, Wr, 0)
    MM8(xr1.h, Wr, 1)

    if (t > 0) {
      // [C] per-producer check; overlap HU(A) with B's retry when possible.
      if (!dead) {
        uint32_t badA = 0, badB = 0;
        asm volatile("s_waitcnt vmcnt(0)" ::: "memory");
        __builtin_amdgcn_sched_barrier(0);
        CHECKW(p0, badA); CHECKW(p1, badA);
        CHECKW(p2, badB); CHECKW(p3, badB);
        bool okA = __all(badA == 0);
        bool okB = __all(badB == 0);
        if (okA && okB) {
          HU(p0, p1, 0);
          HU(p2, p3, 1);
        } else if (okA) {
          HU(p0, p1, 0);  // A valid: compute it while B retries
          int guard = 0;
          for (;;) {
            ISSUE_POLL_B();
            asm volatile("s_waitcnt vmcnt(0)" ::: "memory");
            __builtin_amdgcn_sched_barrier(0);
            badB = 0;
            CHECKW(p2, badB); CHECKW(p3, badB);
            if (__all(badB == 0)) break;
            if (++guard > 200000) { dead = true; break; }
          }
          if (dead) { p2.u = p3.u = (u32x4)(0u); }
          HU(p2, p3, 1);
        } else {
          // A lagging (B may be too): retry missing producer(s) together
          int guard = 0;
          for (;;) {
            if (!okA) ISSUE_POLL_A();
            if (!okB) ISSUE_POLL_B();
            asm volatile("s_waitcnt vmcnt(0)" ::: "memory");
            __builtin_amdgcn_sched_barrier(0);
            badA = badB = 0;
            CHECKW(p0, badA); CHECKW(p1, badA);
            CHECKW(p2, badB); CHECKW(p3, badB);
            okA = __all(badA == 0);
            okB = __all(badB == 0);
            if (okA && okB) break;
            if (++guard > 200000) { dead = true; break; }
          }
          if (dead) { p0.u = p1.u = p2.u = p3.u = (u32x4)(0u); }
          HU(p0, p1, 0);  // fixed order: determinism
          HU(p2, p3, 1);
        }
      } else {
        p0.u = p1.u = p2.u = p3.u = (u32x4)(0u);
        HU(p0, p1, 0);
        HU(p2, p3, 1);
      }
    }

    // [D] prefetch x(t+1) (plain loads) — issued BEFORE stores so [J]
    // vmcnt(2) waits exactly these two
    {
      const bf16_t* xp = xrow + (size_t)((t + 1 < Tdim) ? t + 1 : Tdim - 1) * Ddim;
      asm volatile(
          "global_load_dwordx4 %0, %2, off\n\t"
          "global_load_dwordx4 %1, %2, off offset:64"
          : "=v"(xr0.f), "=v"(xr1.f)
          : "v"(xp) : "memory");
    }

    // [G] k-partial z -> LDS
#pragma unroll
    for (int n = 0; n < 8; ++n) {
      f32x4 av = (n == 0) ? a0 : (n == 1) ? a1 : (n == 2) ? a2 : (n == 3) ? a3
               : (n == 4) ? a4 : (n == 5) ? a5 : (n == 6) ? a6 : a7;
#pragma unroll
      for (int r = 0; r < 4; ++r)
        EX[wv][n >> 1][l4 * 4 + r][(n & 1) * 16 + l15] = av[r];
    }
    __syncthreads();

    // [H] per-element update + direct stamped publish
    float z0 = b4[0], z1 = b4[1], z2 = b4[2], z3 = b4[3];
#pragma unroll
    for (int w = 0; w < 8; ++w) {
      z0 += EX[w][0][urow][ucol];
      z1 += EX[w][1][urow][ucol];
      z2 += EX[w][2][urow][ucol];
      z3 += EX[w][3][urow][ucol];
    }
    float ig = sigmoid_f(z0), fg = sigmoid_f(z1);
    float ct = tanh_f(z2), og = sigmoid_f(z3);
    float cn = tanh_f(fg * cstate + ig * ct);  // module carries ACTIVATED cell
    cstate = cn;
    float h = og * cn;

    bu16 hh; hh.b = (bf16_t)h;
    bu16 hl; hl.b = (bf16_t)(h - (float)hh.b);
    uint32_t pubw = ((uint32_t)hh.u << 16) | ((uint32_t)hl.u & 0xFFF0u) |
                    ((uint32_t)(t + 1) & 15u);
    uint32_t* dst = hpub + ((t & 1) ? BH : 0);
    asm volatile("global_store_dword %0, %1, off sc0 sc1" ::"v"(dst), "v"(pubw)
                 : "memory");
    outp[(size_t)t * Hdim] = h;  // plain store: ack at L2, async writeback

    __syncthreads();  // EX WAR protection (keeps waves in lockstep)

    // [J] wait x loads only (stores are the 2 youngest); store acks retire
    // inside next step's poll window. Safe: h words are self-stamped.
    asm volatile("s_waitcnt vmcnt(2)" ::: "memory");
    __builtin_amdgcn_sched_barrier(0);
  }
}

extern "C" void kernel_launch(void* const* d_in, const int* in_sizes, int n_in,
                              void* d_out, int out_size, void* d_ws, size_t ws_size,
                              hipStream_t stream) {
  const float* x    = (const float*)d_in[0];
  const float* W    = (const float*)d_in[1];
  const float* U    = (const float*)d_in[2];
  const float* bias = (const float*)d_in[3];
  float* out = (float*)d_out;

  unsigned char* ws = (unsigned char*)d_ws;
  // layout: hbuf 256 KB (memset each call) | Wt 2 MB | Ut 2 MB | xb 32 MB
  uint32_t* hbuf = (uint32_t*)ws;
  bf16_t* Wt = (bf16_t*)(ws + 262144);
  bf16_t* Ut = Wt + (size_t)G4H * Ddim;
  bf16_t* xb = Ut + (size_t)G4H * Ddim;

  hipMemsetAsync(hbuf, 0, 262144, stream);

  cast_bf16<<<(Bdim * Tdim * Ddim) / 2048, 256, 0, stream>>>(x, xb);

  dim3 tgrid(G4H / 64, Ddim / 64);
  transpose_bf16_512x2048<<<tgrid, 256, 0, stream>>>(W, Wt);
  transpose_bf16_512x2048<<<tgrid, 256, 0, stream>>>(U, Ut);

  lstm_fused<<<NG * NS, 512, 0, stream>>>(xb, Wt, Ut, bias, out, hbuf);
}

// Round 13
// 1490.860 us; speedup vs baseline: 1.0674x; 1.0674x over previous
//
#include <hip/hip_runtime.h>
#include <hip/hip_bf16.h>
#include <stdint.h>

// LSTM forward, B=64 T=512 D=512 H=512, return_sequences.
// v13 = v11 with EXACTLY ONE change: end-of-step drain vmcnt(0) -> vmcnt(2).
// Waits only the 2 x-prefetch loads; publish/out store acks retire inside
// the NEXT step's poll window ([C] vmcnt(0) still bounds them - they are
// older than the polls). Isolates v12's confound (its per-producer branchy
// retry is fully reverted). Safe: h words are self-stamped (flag-in-data),
// consumers re-verify every word; skew bounded at 1 step by transitive
// block coupling, so parity planes cannot be prematurely overwritten.
// Partition as v11: 64 blocks = 4 groups (g=blk&3, XCDs {g,g+4}) x 16
// slices (32 cols); 512 thr = 8 waves, k-chunk 64; weights in VGPRs;
// stamped u32 MALL comm (sc0 sc1); EX exchange; lockstep barriers.

#define Bdim 64
#define Tdim 512
#define Ddim 512
#define Hdim 512
#define G4H  2048
#define NG 4
#define NS 16
#define BH (Bdim * Hdim)  // u32 elems per parity plane

typedef __bf16 bf16_t;
typedef __bf16 bf16x8 __attribute__((ext_vector_type(8)));
typedef float  f32x4  __attribute__((ext_vector_type(4)));
typedef uint32_t u32x4 __attribute__((ext_vector_type(4)));
union pv128 { u32x4 u; f32x4 f; bf16x8 h; };
union bu16 { bf16_t b; unsigned short u; };

__device__ __forceinline__ float sigmoid_f(float x) {
  return 1.0f / (1.0f + __expf(-x));
}
__device__ __forceinline__ float tanh_f(float x) {
  return 1.0f - 2.0f / (__expf(2.0f * x) + 1.0f);  // stable both tails
}

// src [512][2048] fp32  ->  dst [2048][512] bf16 (transposed)
__global__ void transpose_bf16_512x2048(const float* __restrict__ src,
                                        bf16_t* __restrict__ dst) {
  __shared__ bf16_t tile[64][72];
  int c0 = blockIdx.x * 64;
  int r0 = blockIdx.y * 64;
  int tx = threadIdx.x & 63;
  int ty = threadIdx.x >> 6;
#pragma unroll
  for (int i = 0; i < 64; i += 4)
    tile[ty + i][tx] = (bf16_t)src[(size_t)(r0 + ty + i) * G4H + c0 + tx];
  __syncthreads();
#pragma unroll
  for (int i = 0; i < 64; i += 4)
    dst[(size_t)(c0 + ty + i) * Ddim + r0 + tx] = tile[tx][ty + i];
}

// fp32 -> bf16 elementwise (x pre-conversion), 8 elems/thread
__global__ void cast_bf16(const float* __restrict__ in, bf16_t* __restrict__ out) {
  size_t i = ((size_t)blockIdx.x * blockDim.x + threadIdx.x) * 8;
  f32x4 a = *(const f32x4*)(in + i);
  f32x4 b = *(const f32x4*)(in + i + 4);
  bf16x8 v;
#pragma unroll
  for (int j = 0; j < 4; ++j) { v[j] = (bf16_t)a[j]; v[j + 4] = (bf16_t)b[j]; }
  *(bf16x8*)(out + i) = v;
}

#define MFMA16(A, B, C) __builtin_amdgcn_mfma_f32_16x16x32_bf16(A, B, C, 0, 0, 0)

// 4 stamped h loads (k-chunk 64 = 2 x 32-col chunks), MALL-direct
#define ISSUE_POLL()                                                         \
  asm volatile(                                                              \
      "global_load_dwordx4 %0, %4, off sc0 sc1\n\t"                          \
      "global_load_dwordx4 %1, %4, off offset:16 sc0 sc1\n\t"                \
      "global_load_dwordx4 %2, %4, off offset:128 sc0 sc1\n\t"               \
      "global_load_dwordx4 %3, %4, off offset:144 sc0 sc1"                   \
      : "=v"(p0.f), "=v"(p1.f), "=v"(p2.f), "=v"(p3.f)                       \
      : "v"(hb)                                                              \
      : "memory")

#define CHECK(P)                                                             \
  do {                                                                       \
    bad |= (P.u[0] ^ st) & 15u;                                              \
    bad |= (P.u[1] ^ st) & 15u;                                              \
    bad |= (P.u[2] ^ st) & 15u;                                              \
    bad |= (P.u[3] ^ st) & 15u;                                              \
  } while (0)

// 8 MFMAs over the 8 N-tiles with A-operand AV and k-frag c
#define MM8(AV, WU, c)                                                       \
  a0 = MFMA16(AV, WU[0][c], a0);                                             \
  a1 = MFMA16(AV, WU[1][c], a1);                                             \
  a2 = MFMA16(AV, WU[2][c], a2);                                             \
  a3 = MFMA16(AV, WU[3][c], a3);                                             \
  a4 = MFMA16(AV, WU[4][c], a4);                                             \
  a5 = MFMA16(AV, WU[5][c], a5);                                             \
  a6 = MFMA16(AV, WU[6][c], a6);                                             \
  a7 = MFMA16(AV, WU[7][c], a7);

// unpack chunk c (8 u32 -> hi/lo bf16x8) and run 16 MFMAs
#define HU(PA, PB, c)                                                        \
  do {                                                                       \
    pv128 hi_, lo_;                                                          \
    hi_.u[0] = (PA.u[0] >> 16) | (PA.u[1] & 0xFFFF0000u);                    \
    hi_.u[1] = (PA.u[2] >> 16) | (PA.u[3] & 0xFFFF0000u);                    \
    hi_.u[2] = (PB.u[0] >> 16) | (PB.u[1] & 0xFFFF0000u);                    \
    hi_.u[3] = (PB.u[2] >> 16) | (PB.u[3] & 0xFFFF0000u);                    \
    lo_.u[0] = (PA.u[0] & 0xFFF0u) | ((PA.u[1] & 0xFFF0u) << 16);            \
    lo_.u[1] = (PA.u[2] & 0xFFF0u) | ((PA.u[3] & 0xFFF0u) << 16);            \
    lo_.u[2] = (PB.u[0] & 0xFFF0u) | ((PB.u[1] & 0xFFF0u) << 16);            \
    lo_.u[3] = (PB.u[2] & 0xFFF0u) | ((PB.u[3] & 0xFFF0u) << 16);            \
    MM8(hi_.h, Ur, c)                                                        \
    MM8(lo_.h, Ur, c)                                                        \
  } while (0)

__launch_bounds__(512, 1)
__global__ void lstm_fused(const bf16_t* __restrict__ xb,   // [B][T][D] bf16
                           const bf16_t* __restrict__ Wt,   // [2048][512] bf16
                           const bf16_t* __restrict__ Ut,   // [2048][512] bf16
                           const float* __restrict__ bias,  // [2048]
                           float* __restrict__ out,         // [B][T][H] fp32
                           uint32_t* __restrict__ hbuf) {   // [2 par][B][H] u32
  __shared__ float EX[8][4][16][36];  // [wave][gate][row][col pad36]

  const int blk  = blockIdx.x;
  const int g    = blk & 3;            // group spread: XCDs {g, g+4} only
  const int s    = blk >> 2;           // 0..15
  const int wv   = threadIdx.x >> 6;   // 0..7
  const int lane = threadIdx.x & 63;
  const int l15  = lane & 15;
  const int l4   = lane >> 4;
  const int b0   = g * 16;
  const int hc0  = s * 32;
  const int k0   = wv * 64;            // this wave's k-chunk

  // ---- weights into registers (MFMA B-frag order), 8 N-tiles x 2 k-frags ----
  bf16x8 Wr[8][2], Ur[8][2];
#pragma unroll
  for (int n = 0; n < 8; ++n) {
    int zc = (n >> 1) * Hdim + hc0 + (n & 1) * 16 + l15;
    const bf16_t* wsrc = Wt + (size_t)zc * Ddim + k0 + l4 * 8;
    const bf16_t* usrc = Ut + (size_t)zc * Ddim + k0 + l4 * 8;
#pragma unroll
    for (int c = 0; c < 2; ++c) {
      Wr[n][c] = *(const bf16x8*)(wsrc + c * 32);
      Ur[n][c] = *(const bf16x8*)(usrc + c * 32);
    }
  }

  // update-thread mapping: one h element per thread
  const int urow = threadIdx.x >> 5;   // 0..15
  const int ucol = threadIdx.x & 31;   // 0..31
  float b4[4];
#pragma unroll
  for (int G = 0; G < 4; ++G) b4[G] = bias[G * Hdim + hc0 + ucol];
  float cstate = 0.f;
  float* outp = out + (size_t)(b0 + urow) * Tdim * Hdim + hc0 + ucol;
  uint32_t* hpub = hbuf + (size_t)(b0 + urow) * Hdim + hc0 + ucol;
  const uint32_t* hrd = hbuf + (size_t)(b0 + l15) * Hdim + k0 + l4 * 8;
  const bf16_t* xrow = xb + (size_t)(b0 + l15) * Tdim * Ddim + k0 + l4 * 8;

  // ---- prologue: x(0) into regs (plain loads) ----
  pv128 xr0, xr1;
  asm volatile(
      "global_load_dwordx4 %0, %2, off\n\t"
      "global_load_dwordx4 %1, %2, off offset:64\n\t"
      "s_waitcnt vmcnt(0)"
      : "=v"(xr0.f), "=v"(xr1.f)
      : "v"(xrow) : "memory");
  __builtin_amdgcn_sched_barrier(0);

  bool dead = false;

  for (int t = 0; t < Tdim; ++t) {
    pv128 p0, p1, p2, p3;
    const uint32_t st = (uint32_t)t & 15u;  // stamp on h_{t-1}
    const uint32_t* hb = hrd + (((t - 1) & 1) ? BH : 0);

    // [P] issue stamped h polls; they fly during x@W
    if (t > 0 && !dead) {
      ISSUE_POLL();
      __builtin_amdgcn_sched_barrier(0);
    }

    // [A] x_t @ W (registers only)
    f32x4 a0 = {0, 0, 0, 0}, a1 = {0, 0, 0, 0}, a2 = {0, 0, 0, 0}, a3 = {0, 0, 0, 0};
    f32x4 a4 = {0, 0, 0, 0}, a5 = {0, 0, 0, 0}, a6 = {0, 0, 0, 0}, a7 = {0, 0, 0, 0};
    MM8(xr0.h, Wr, 0)
    MM8(xr1.h, Wr, 1)

    if (t > 0) {
      // [C] poll until all 16 words carry stamp t
      if (!dead) {
        int guard = 0;
        for (;;) {
          asm volatile("s_waitcnt vmcnt(0)" ::: "memory");
          __builtin_amdgcn_sched_barrier(0);
          uint32_t bad = 0;
          CHECK(p0); CHECK(p1); CHECK(p2); CHECK(p3);
          if (__all(bad == 0)) break;
          if (++guard > 200000) { dead = true; break; }
          ISSUE_POLL();
          __builtin_amdgcn_sched_barrier(0);
        }
      } else {
        p0.u = p1.u = p2.u = p3.u = (u32x4)(0u);
      }
      // [U] unpack + h @ U (hi + lo)
      HU(p0, p1, 0);
      HU(p2, p3, 1);
    }

    // [D] prefetch x(t+1) (plain loads) — issued BEFORE stores so [J]
    // vmcnt(2) waits exactly these two
    {
      const bf16_t* xp = xrow + (size_t)((t + 1 < Tdim) ? t + 1 : Tdim - 1) * Ddim;
      asm volatile(
          "global_load_dwordx4 %0, %2, off\n\t"
          "global_load_dwordx4 %1, %2, off offset:64"
          : "=v"(xr0.f), "=v"(xr1.f)
          : "v"(xp) : "memory");
    }

    // [G] k-partial z -> LDS
#pragma unroll
    for (int n = 0; n < 8; ++n) {
      f32x4 av = (n == 0) ? a0 : (n == 1) ? a1 : (n == 2) ? a2 : (n == 3) ? a3
               : (n == 4) ? a4 : (n == 5) ? a5 : (n == 6) ? a6 : a7;
#pragma unroll
      for (int r = 0; r < 4; ++r)
        EX[wv][n >> 1][l4 * 4 + r][(n & 1) * 16 + l15] = av[r];
    }
    __syncthreads();

    // [H] per-element update + direct stamped publish
    float z0 = b4[0], z1 = b4[1], z2 = b4[2], z3 = b4[3];
#pragma unroll
    for (int w = 0; w < 8; ++w) {
      z0 += EX[w][0][urow][ucol];
      z1 += EX[w][1][urow][ucol];
      z2 += EX[w][2][urow][ucol];
      z3 += EX[w][3][urow][ucol];
    }
    float ig = sigmoid_f(z0), fg = sigmoid_f(z1);
    float ct = tanh_f(z2), og = sigmoid_f(z3);
    float cn = tanh_f(fg * cstate + ig * ct);  // module carries ACTIVATED cell
    cstate = cn;
    float h = og * cn;

    bu16 hh; hh.b = (bf16_t)h;
    bu16 hl; hl.b = (bf16_t)(h - (float)hh.b);
    uint32_t pubw = ((uint32_t)hh.u << 16) | ((uint32_t)hl.u & 0xFFF0u) |
                    ((uint32_t)(t + 1) & 15u);
    uint32_t* dst = hpub + ((t & 1) ? BH : 0);
    asm volatile("global_store_dword %0, %1, off sc0 sc1" ::"v"(dst), "v"(pubw)
                 : "memory");
    outp[(size_t)t * Hdim] = h;  // plain store: ack at L2, async writeback

    __syncthreads();  // EX WAR protection (keeps waves in lockstep)

    // [J] wait x loads only (stores are the 2 youngest); store acks retire
    // inside next step's poll window ([C] vmcnt(0) bounds them).
    asm volatile("s_waitcnt vmcnt(2)" ::: "memory");
    __builtin_amdgcn_sched_barrier(0);
  }
}

extern "C" void kernel_launch(void* const* d_in, const int* in_sizes, int n_in,
                              void* d_out, int out_size, void* d_ws, size_t ws_size,
                              hipStream_t stream) {
  const float* x    = (const float*)d_in[0];
  const float* W    = (const float*)d_in[1];
  const float* U    = (const float*)d_in[2];
  const float* bias = (const float*)d_in[3];
  float* out = (float*)d_out;

  unsigned char* ws = (unsigned char*)d_ws;
  // layout: hbuf 256 KB (memset each call) | Wt 2 MB | Ut 2 MB | xb 32 MB
  uint32_t* hbuf = (uint32_t*)ws;
  bf16_t* Wt = (bf16_t*)(ws + 262144);
  bf16_t* Ut = Wt + (size_t)G4H * Ddim;
  bf16_t* xb = Ut + (size_t)G4H * Ddim;

  hipMemsetAsync(hbuf, 0, 262144, stream);

  cast_bf16<<<(Bdim * Tdim * Ddim) / 2048, 256, 0, stream>>>(x, xb);

  dim3 tgrid(G4H / 64, Ddim / 64);
  transpose_bf16_512x2048<<<tgrid, 256, 0, stream>>>(W, Wt);
  transpose_bf16_512x2048<<<tgrid, 256, 0, stream>>>(U, Ut);

  lstm_fused<<<NG * NS, 512, 0, stream>>>(xb, Wt, Ut, bias, out, hbuf);
}

// Round 16
// 1359.939 us; speedup vs baseline: 1.1701x; 1.0963x over previous
//
#include <hip/hip_runtime.h>
#include <hip/hip_bf16.h>
#include <stdint.h>

// LSTM forward, B=64 T=512 D=512 H=512, return_sequences.
// v17 = EXACT revert to v11, the verified optimum (1381us, absmax 0.0039).
// Post-v11 record: v12 (drain relax + branchy retry) -15%; v13 (drain relax
// isolated) -8% -> publish-ack pacing is load-bearing; v15/v16 (pipelined
// retry) both incorrect -> compiler may spill regs pending in-flight load
// writes; line closed. Kernel is synchronization-latency-bound: ~900cy
// compute + ~2 serialized MALL RTs/step (irreducible for cross-XCD
// recurrence comm; XCD-local L2 comm is not coherent per v5).
// Structure: 64 blocks = 4 groups (g=blk&3 -> XCDs {g,g+4}) x 16 slices
// (32 cols); 512 thr = 8 waves, k-chunk 64/wave; weights in VGPRs;
// flag-in-data stamped u32 MALL comm (sc0 sc1, bf16 hi/lo + 4-bit stamp,
// parity planes); EX LDS exchange; lockstep barriers; full [J] drain.

#define Bdim 64
#define Tdim 512
#define Ddim 512
#define Hdim 512
#define G4H  2048
#define NG 4
#define NS 16
#define BH (Bdim * Hdim)  // u32 elems per parity plane

typedef __bf16 bf16_t;
typedef __bf16 bf16x8 __attribute__((ext_vector_type(8)));
typedef float  f32x4  __attribute__((ext_vector_type(4)));
typedef uint32_t u32x4 __attribute__((ext_vector_type(4)));
union pv128 { u32x4 u; f32x4 f; bf16x8 h; };
union bu16 { bf16_t b; unsigned short u; };

__device__ __forceinline__ float sigmoid_f(float x) {
  return 1.0f / (1.0f + __expf(-x));
}
__device__ __forceinline__ float tanh_f(float x) {
  return 1.0f - 2.0f / (__expf(2.0f * x) + 1.0f);  // stable both tails
}

// src [512][2048] fp32  ->  dst [2048][512] bf16 (transposed)
__global__ void transpose_bf16_512x2048(const float* __restrict__ src,
                                        bf16_t* __restrict__ dst) {
  __shared__ bf16_t tile[64][72];
  int c0 = blockIdx.x * 64;
  int r0 = blockIdx.y * 64;
  int tx = threadIdx.x & 63;
  int ty = threadIdx.x >> 6;
#pragma unroll
  for (int i = 0; i < 64; i += 4)
    tile[ty + i][tx] = (bf16_t)src[(size_t)(r0 + ty + i) * G4H + c0 + tx];
  __syncthreads();
#pragma unroll
  for (int i = 0; i < 64; i += 4)
    dst[(size_t)(c0 + ty + i) * Ddim + r0 + tx] = tile[tx][ty + i];
}

// fp32 -> bf16 elementwise (x pre-conversion), 8 elems/thread
__global__ void cast_bf16(const float* __restrict__ in, bf16_t* __restrict__ out) {
  size_t i = ((size_t)blockIdx.x * blockDim.x + threadIdx.x) * 8;
  f32x4 a = *(const f32x4*)(in + i);
  f32x4 b = *(const f32x4*)(in + i + 4);
  bf16x8 v;
#pragma unroll
  for (int j = 0; j < 4; ++j) { v[j] = (bf16_t)a[j]; v[j + 4] = (bf16_t)b[j]; }
  *(bf16x8*)(out + i) = v;
}

#define MFMA16(A, B, C) __builtin_amdgcn_mfma_f32_16x16x32_bf16(A, B, C, 0, 0, 0)

// 4 stamped h loads (k-chunk 64 = 2 x 32-col chunks), MALL-direct
#define ISSUE_POLL()                                                         \
  asm volatile(                                                              \
      "global_load_dwordx4 %0, %4, off sc0 sc1\n\t"                          \
      "global_load_dwordx4 %1, %4, off offset:16 sc0 sc1\n\t"                \
      "global_load_dwordx4 %2, %4, off offset:128 sc0 sc1\n\t"               \
      "global_load_dwordx4 %3, %4, off offset:144 sc0 sc1"                   \
      : "=v"(p0.f), "=v"(p1.f), "=v"(p2.f), "=v"(p3.f)                       \
      : "v"(hb)                                                              \
      : "memory")

#define CHECK(P)                                                             \
  do {                                                                       \
    bad |= (P.u[0] ^ st) & 15u;                                              \
    bad |= (P.u[1] ^ st) & 15u;                                              \
    bad |= (P.u[2] ^ st) & 15u;                                              \
    bad |= (P.u[3] ^ st) & 15u;                                              \
  } while (0)

// 8 MFMAs over the 8 N-tiles with A-operand AV and k-frag c
#define MM8(AV, WU, c)                                                       \
  a0 = MFMA16(AV, WU[0][c], a0);                                             \
  a1 = MFMA16(AV, WU[1][c], a1);                                             \
  a2 = MFMA16(AV, WU[2][c], a2);                                             \
  a3 = MFMA16(AV, WU[3][c], a3);                                             \
  a4 = MFMA16(AV, WU[4][c], a4);                                             \
  a5 = MFMA16(AV, WU[5][c], a5);                                             \
  a6 = MFMA16(AV, WU[6][c], a6);                                             \
  a7 = MFMA16(AV, WU[7][c], a7);

// unpack chunk c (8 u32 -> hi/lo bf16x8) and run 16 MFMAs
#define HU(PA, PB, c)                                                        \
  do {                                                                       \
    pv128 hi_, lo_;                                                          \
    hi_.u[0] = (PA.u[0] >> 16) | (PA.u[1] & 0xFFFF0000u);                    \
    hi_.u[1] = (PA.u[2] >> 16) | (PA.u[3] & 0xFFFF0000u);                    \
    hi_.u[2] = (PB.u[0] >> 16) | (PB.u[1] & 0xFFFF0000u);                    \
    hi_.u[3] = (PB.u[2] >> 16) | (PB.u[3] & 0xFFFF0000u);                    \
    lo_.u[0] = (PA.u[0] & 0xFFF0u) | ((PA.u[1] & 0xFFF0u) << 16);            \
    lo_.u[1] = (PA.u[2] & 0xFFF0u) | ((PA.u[3] & 0xFFF0u) << 16);            \
    lo_.u[2] = (PB.u[0] & 0xFFF0u) | ((PB.u[1] & 0xFFF0u) << 16);            \
    lo_.u[3] = (PB.u[2] & 0xFFF0u) | ((PB.u[3] & 0xFFF0u) << 16);            \
    MM8(hi_.h, Ur, c)                                                        \
    MM8(lo_.h, Ur, c)                                                        \
  } while (0)

__launch_bounds__(512, 1)
__global__ void lstm_fused(const bf16_t* __restrict__ xb,   // [B][T][D] bf16
                           const bf16_t* __restrict__ Wt,   // [2048][512] bf16
                           const bf16_t* __restrict__ Ut,   // [2048][512] bf16
                           const float* __restrict__ bias,  // [2048]
                           float* __restrict__ out,         // [B][T][H] fp32
                           uint32_t* __restrict__ hbuf) {   // [2 par][B][H] u32
  __shared__ float EX[8][4][16][36];  // [wave][gate][row][col pad36]

  const int blk  = blockIdx.x;
  const int g    = blk & 3;            // group spread: XCDs {g, g+4} only
  const int s    = blk >> 2;           // 0..15
  const int wv   = threadIdx.x >> 6;   // 0..7
  const int lane = threadIdx.x & 63;
  const int l15  = lane & 15;
  const int l4   = lane >> 4;
  const int b0   = g * 16;
  const int hc0  = s * 32;
  const int k0   = wv * 64;            // this wave's k-chunk

  // ---- weights into registers (MFMA B-frag order), 8 N-tiles x 2 k-frags ----
  bf16x8 Wr[8][2], Ur[8][2];
#pragma unroll
  for (int n = 0; n < 8; ++n) {
    int zc = (n >> 1) * Hdim + hc0 + (n & 1) * 16 + l15;
    const bf16_t* wsrc = Wt + (size_t)zc * Ddim + k0 + l4 * 8;
    const bf16_t* usrc = Ut + (size_t)zc * Ddim + k0 + l4 * 8;
#pragma unroll
    for (int c = 0; c < 2; ++c) {
      Wr[n][c] = *(const bf16x8*)(wsrc + c * 32);
      Ur[n][c] = *(const bf16x8*)(usrc + c * 32);
    }
  }

  // update-thread mapping: one h element per thread
  const int urow = threadIdx.x >> 5;   // 0..15
  const int ucol = threadIdx.x & 31;   // 0..31
  float b4[4];
#pragma unroll
  for (int G = 0; G < 4; ++G) b4[G] = bias[G * Hdim + hc0 + ucol];
  float cstate = 0.f;
  float* outp = out + (size_t)(b0 + urow) * Tdim * Hdim + hc0 + ucol;
  uint32_t* hpub = hbuf + (size_t)(b0 + urow) * Hdim + hc0 + ucol;
  const uint32_t* hrd = hbuf + (size_t)(b0 + l15) * Hdim + k0 + l4 * 8;
  const bf16_t* xrow = xb + (size_t)(b0 + l15) * Tdim * Ddim + k0 + l4 * 8;

  // ---- prologue: x(0) into regs (plain loads) ----
  pv128 xr0, xr1;
  asm volatile(
      "global_load_dwordx4 %0, %2, off\n\t"
      "global_load_dwordx4 %1, %2, off offset:64\n\t"
      "s_waitcnt vmcnt(0)"
      : "=v"(xr0.f), "=v"(xr1.f)
      : "v"(xrow) : "memory");
  __builtin_amdgcn_sched_barrier(0);

  bool dead = false;

  for (int t = 0; t < Tdim; ++t) {
    pv128 p0, p1, p2, p3;
    const uint32_t st = (uint32_t)t & 15u;  // stamp on h_{t-1}
    const uint32_t* hb = hrd + (((t - 1) & 1) ? BH : 0);

    // [P] issue stamped h polls; they fly during x@W
    if (t > 0 && !dead) {
      ISSUE_POLL();
      __builtin_amdgcn_sched_barrier(0);
    }

    // [A] x_t @ W (registers only)
    f32x4 a0 = {0, 0, 0, 0}, a1 = {0, 0, 0, 0}, a2 = {0, 0, 0, 0}, a3 = {0, 0, 0, 0};
    f32x4 a4 = {0, 0, 0, 0}, a5 = {0, 0, 0, 0}, a6 = {0, 0, 0, 0}, a7 = {0, 0, 0, 0};
    MM8(xr0.h, Wr, 0)
    MM8(xr1.h, Wr, 1)

    if (t > 0) {
      // [C] poll until all 16 words carry stamp t
      if (!dead) {
        int guard = 0;
        for (;;) {
          asm volatile("s_waitcnt vmcnt(0)" ::: "memory");
          __builtin_amdgcn_sched_barrier(0);
          uint32_t bad = 0;
          CHECK(p0); CHECK(p1); CHECK(p2); CHECK(p3);
          if (__all(bad == 0)) break;
          if (++guard > 200000) { dead = true; break; }
          ISSUE_POLL();
          __builtin_amdgcn_sched_barrier(0);
        }
      } else {
        p0.u = p1.u = p2.u = p3.u = (u32x4)(0u);
      }
      // [U] unpack + h @ U (hi + lo)
      HU(p0, p1, 0);
      HU(p2, p3, 1);
    }

    // [D] prefetch x(t+1) (plain loads)
    {
      const bf16_t* xp = xrow + (size_t)((t + 1 < Tdim) ? t + 1 : Tdim - 1) * Ddim;
      asm volatile(
          "global_load_dwordx4 %0, %2, off\n\t"
          "global_load_dwordx4 %1, %2, off offset:64"
          : "=v"(xr0.f), "=v"(xr1.f)
          : "v"(xp) : "memory");
    }

    // [G] k-partial z -> LDS
#pragma unroll
    for (int n = 0; n < 8; ++n) {
      f32x4 av = (n == 0) ? a0 : (n == 1) ? a1 : (n == 2) ? a2 : (n == 3) ? a3
               : (n == 4) ? a4 : (n == 5) ? a5 : (n == 6) ? a6 : a7;
#pragma unroll
      for (int r = 0; r < 4; ++r)
        EX[wv][n >> 1][l4 * 4 + r][(n & 1) * 16 + l15] = av[r];
    }
    __syncthreads();

    // [H] per-element update + direct stamped publish
    float z0 = b4[0], z1 = b4[1], z2 = b4[2], z3 = b4[3];
#pragma unroll
    for (int w = 0; w < 8; ++w) {
      z0 += EX[w][0][urow][ucol];
      z1 += EX[w][1][urow][ucol];
      z2 += EX[w][2][urow][ucol];
      z3 += EX[w][3][urow][ucol];
    }
    float ig = sigmoid_f(z0), fg = sigmoid_f(z1);
    float ct = tanh_f(z2), og = sigmoid_f(z3);
    float cn = tanh_f(fg * cstate + ig * ct);  // module carries ACTIVATED cell
    cstate = cn;
    float h = og * cn;

    bu16 hh; hh.b = (bf16_t)h;
    bu16 hl; hl.b = (bf16_t)(h - (float)hh.b);
    uint32_t pubw = ((uint32_t)hh.u << 16) | ((uint32_t)hl.u & 0xFFF0u) |
                    ((uint32_t)(t + 1) & 15u);
    uint32_t* dst = hpub + ((t & 1) ? BH : 0);
    asm volatile("global_store_dword %0, %1, off sc0 sc1" ::"v"(dst), "v"(pubw)
                 : "memory");
    outp[(size_t)t * Hdim] = h;  // plain store: ack at L2, async writeback

    __syncthreads();  // EX WAR protection (keeps waves in lockstep)

    // [J] full drain: publish-ack pacing is load-bearing (r12/r13)
    asm volatile("s_waitcnt vmcnt(0)" ::: "memory");
    __builtin_amdgcn_sched_barrier(0);
  }
}

extern "C" void kernel_launch(void* const* d_in, const int* in_sizes, int n_in,
                              void* d_out, int out_size, void* d_ws, size_t ws_size,
                              hipStream_t stream) {
  const float* x    = (const float*)d_in[0];
  const float* W    = (const float*)d_in[1];
  const float* U    = (const float*)d_in[2];
  const float* bias = (const float*)d_in[3];
  float* out = (float*)d_out;

  unsigned char* ws = (unsigned char*)d_ws;
  // layout: hbuf 256 KB (memset each call) | Wt 2 MB | Ut 2 MB | xb 32 MB
  uint32_t* hbuf = (uint32_t*)ws;
  bf16_t* Wt = (bf16_t*)(ws + 262144);
  bf16_t* Ut = Wt + (size_t)G4H * Ddim;
  bf16_t* xb = Ut + (size_t)G4H * Ddim;

  hipMemsetAsync(hbuf, 0, 262144, stream);

  cast_bf16<<<(Bdim * Tdim * Ddim) / 2048, 256, 0, stream>>>(x, xb);

  dim3 tgrid(G4H / 64, Ddim / 64);
  transpose_bf16_512x2048<<<tgrid, 256, 0, stream>>>(W, Wt);
  transpose_bf16_512x2048<<<tgrid, 256, 0, stream>>>(U, Ut);

  lstm_fused<<<NG * NS, 512, 0, stream>>>(xb, Wt, Ut, bias, out, hbuf);
}